// Round 2
// baseline (476.618 us; speedup 1.0000x reference)
//
#include <hip/hip_runtime.h>
#include <hip/hip_bf16.h>
#include <cstdint>

#define N_NODES 50000
#define N_EDGES 800000
#define D 128

typedef __attribute__((ext_vector_type(4))) float f32x4;
typedef __attribute__((ext_vector_type(8))) short s16x8;

__device__ __forceinline__ float bflo(uint32_t v) { return __uint_as_float(v << 16); }
__device__ __forceinline__ float bfhi(uint32_t v) { return __uint_as_float(v & 0xffff0000u); }
__device__ __forceinline__ uint32_t f2b(float f) {
    uint32_t x = __float_as_uint(f);
    uint32_t r = x + 0x7fffu + ((x >> 16) & 1u);   // RNE to bf16
    return r >> 16;
}
__device__ __forceinline__ uint32_t pack2(float lo, float hi) {
    return f2b(lo) | (f2b(hi) << 16);
}

// ---------------- prep: x -> bf16, weights -> concatenated bf16 [Wl|Wr] ----
__global__ void prep_k(const float* __restrict__ x,
                       const float* __restrict__ Wl0, const float* __restrict__ Wr0,
                       const float* __restrict__ Wl1, const float* __restrict__ Wr1,
                       const float* __restrict__ Wl2, const float* __restrict__ Wr2,
                       uint32_t* __restrict__ X0, uint32_t* __restrict__ Wc)
{
    const int NX = N_NODES * D / 2;      // 3,200,000 uints
    const int NW = 3 * 128 * 128;        // 49,152 uints
    for (int i = blockIdx.x * blockDim.x + threadIdx.x; i < NX + NW;
         i += gridDim.x * blockDim.x) {
        if (i < NX) {
            const float2 v = reinterpret_cast<const float2*>(x)[i];
            X0[i] = pack2(v.x, v.y);
        } else {
            int j = i - NX;
            int l = j / 16384;
            int r = j % 16384;
            int n = r >> 7;
            int k2 = (r & 127) * 2;
            const float* Wl = (l == 0) ? Wl0 : (l == 1) ? Wl1 : Wl2;
            const float* Wr = (l == 0) ? Wr0 : (l == 1) ? Wr1 : Wr2;
            float a, b;
            if (k2 < 128) { a = Wl[n * 128 + k2];       b = Wl[n * 128 + k2 + 1]; }
            else          { a = Wr[n * 128 + k2 - 128]; b = Wr[n * 128 + k2 - 127]; }
            Wc[j] = pack2(a, b);
        }
    }
}

// ---------------- CSR build ------------------------------------------------
__global__ void degree_k(const int* __restrict__ dst, int* __restrict__ cnt) {
    int e = blockIdx.x * blockDim.x + threadIdx.x;
    if (e < N_EDGES) atomicAdd(&cnt[dst[e]], 1);
}

__global__ void scan1_k(const int* __restrict__ cnt, int* __restrict__ bsum) {
    __shared__ int red[256];
    int i = blockIdx.x * 256 + threadIdx.x;
    int v = (i < N_NODES) ? cnt[i] : 0;
    red[threadIdx.x] = v;
    __syncthreads();
    for (int s = 128; s > 0; s >>= 1) {
        if (threadIdx.x < s) red[threadIdx.x] += red[threadIdx.x + s];
        __syncthreads();
    }
    if (threadIdx.x == 0) bsum[blockIdx.x] = red[0];
}

__global__ void scan2_k(int* __restrict__ bsum) {   // 196 entries -> exclusive
    __shared__ int s[256];
    int t = threadIdx.x;
    int v = (t < 196) ? bsum[t] : 0;
    s[t] = v;
    __syncthreads();
    for (int d = 1; d < 256; d <<= 1) {
        int tmp = (t >= d) ? s[t - d] : 0;
        __syncthreads();
        s[t] += tmp;
        __syncthreads();
    }
    if (t < 196) bsum[t] = s[t] - v;
}

__global__ void scan3_k(const int* __restrict__ cnt, const int* __restrict__ bsum,
                        int* __restrict__ rowptr) {
    __shared__ int s[256];
    int i = blockIdx.x * 256 + threadIdx.x;
    int t = threadIdx.x;
    int v = (i < N_NODES) ? cnt[i] : 0;
    s[t] = v;
    __syncthreads();
    for (int d = 1; d < 256; d <<= 1) {
        int tmp = (t >= d) ? s[t - d] : 0;
        __syncthreads();
        s[t] += tmp;
        __syncthreads();
    }
    if (i < N_NODES) rowptr[i] = bsum[blockIdx.x] + s[t] - v;
    if (i == 0) rowptr[N_NODES] = N_EDGES;
}

__global__ void fill_adj_k(const int* __restrict__ src, const int* __restrict__ dst,
                           const int* __restrict__ rowptr, int* __restrict__ cursor,
                           int* __restrict__ adj) {
    int e = blockIdx.x * blockDim.x + threadIdx.x;
    if (e < N_EDGES) {
        int d = dst[e];
        int pos = atomicAdd(&cursor[d], 1);
        adj[rowptr[d] + pos] = src[e];
    }
}

// ---------------- mean aggregation: one wave per node ----------------------
__global__ __launch_bounds__(256) void agg_k(const uint32_t* __restrict__ inB,
                                             const int* __restrict__ rowptr,
                                             const int* __restrict__ adj,
                                             uint32_t* __restrict__ meanb)
{
    int wid = threadIdx.x >> 6;
    int lane = threadIdx.x & 63;
    int n = blockIdx.x * 4 + wid;
    if (n >= N_NODES) return;
    int start = rowptr[n], end = rowptr[n + 1];
    float a0 = 0.f, a1 = 0.f;
    for (int base = start; base < end; base += 64) {
        int m = end - base;
        if (m > 64) m = 64;
        int idx = 0;
        if (base + lane < end) idx = adj[base + lane];
        for (int j = 0; j < m; ++j) {
            int sN = __shfl(idx, j, 64);
            uint32_t v = inB[sN * 64 + lane];
            a0 += bflo(v);
            a1 += bfhi(v);
        }
    }
    int deg = end - start;
    float sc = 1.0f / (float)(deg > 0 ? deg : 1);
    meanb[n * 64 + lane] = pack2(a0 * sc, a1 * sc);
}

// ---------------- fused GEMM: [mean | in] @ [Wl | Wr]^T + bias -------------
template <int LAYER>
__global__ __launch_bounds__(256) void gemm_k(const uint32_t* __restrict__ meanb,
                                              const uint32_t* __restrict__ inB,
                                              const uint32_t* __restrict__ Wc,
                                              const float* __restrict__ bias,
                                              void* __restrict__ outp)
{
    const int lane = threadIdx.x & 63;
    const int wid = threadIdx.x >> 6;
    const int rowBase = blockIdx.x * 128 + wid * 32;
    const int l15 = lane & 15;
    const int kc = lane >> 4;
    int m0 = rowBase + l15;
    int m1 = m0 + 16;
    int m0c = m0 < N_NODES ? m0 : N_NODES - 1;
    int m1c = m1 < N_NODES ? m1 : N_NODES - 1;
    const uint32_t* Wl = Wc + LAYER * 16384;

    f32x4 acc[2][8];
#pragma unroll
    for (int a = 0; a < 2; ++a)
#pragma unroll
        for (int b = 0; b < 8; ++b) acc[a][b] = (f32x4){0.f, 0.f, 0.f, 0.f};

#pragma unroll
    for (int ks = 0; ks < 8; ++ks) {
        const uint32_t* Asrc = (ks < 4) ? meanb : inB;
        const int koff = (ks & 3) * 16 + kc * 4;
        s16x8 a0 = *reinterpret_cast<const s16x8*>(Asrc + m0c * 64 + koff);
        s16x8 a1 = *reinterpret_cast<const s16x8*>(Asrc + m1c * 64 + koff);
#pragma unroll
        for (int nf = 0; nf < 8; ++nf) {
            s16x8 b = *reinterpret_cast<const s16x8*>(Wl + (nf * 16 + l15) * 128 + ks * 16 + kc * 4);
            acc[0][nf] = __builtin_amdgcn_mfma_f32_16x16x32_bf16(a0, b, acc[0][nf], 0, 0, 0);
            acc[1][nf] = __builtin_amdgcn_mfma_f32_16x16x32_bf16(a1, b, acc[1][nf], 0, 0, 0);
        }
    }

    const int rb = rowBase + (lane >> 4) * 4;
#pragma unroll
    for (int mf = 0; mf < 2; ++mf) {
#pragma unroll
        for (int nf = 0; nf < 8; ++nf) {
            int col = nf * 16 + l15;
            float bia = bias[col];
#pragma unroll
            for (int r = 0; r < 4; ++r) {
                int row = rb + mf * 16 + r;
                if (row < N_NODES) {
                    float v = acc[mf][nf][r] + bia;
                    if (LAYER == 0) v = v > 0.f ? v : 0.f;
                    if (LAYER == 2)
                        ((float*)outp)[row * 128 + col] = v;
                    else
                        ((unsigned short*)outp)[row * 128 + col] = (unsigned short)f2b(v);
                }
            }
        }
    }
}

// ---------------- BatchNorm ------------------------------------------------
__global__ void bn_stats_k(const uint32_t* __restrict__ G2, float* __restrict__ colsums) {
    __shared__ float4 red[256];
    int c2 = threadIdx.x & 63;
    int rg = threadIdx.x >> 6;
    float s0 = 0, q0 = 0, s1 = 0, q1 = 0;
    for (int r = blockIdx.x * 4 + rg; r < N_NODES; r += gridDim.x * 4) {
        uint32_t v = G2[r * 64 + c2];
        float f0 = bflo(v), f1 = bfhi(v);
        s0 += f0; q0 += f0 * f0;
        s1 += f1; q1 += f1 * f1;
    }
    red[threadIdx.x] = make_float4(s0, q0, s1, q1);
    __syncthreads();
    if (threadIdx.x < 64) {
        float4 a = red[threadIdx.x], b = red[threadIdx.x + 64];
        float4 c = red[threadIdx.x + 128], d = red[threadIdx.x + 192];
        atomicAdd(&colsums[c2 * 2],       a.x + b.x + c.x + d.x);
        atomicAdd(&colsums[c2 * 2 + 1],   a.z + b.z + c.z + d.z);
        atomicAdd(&colsums[128 + c2 * 2],     a.y + b.y + c.y + d.y);
        atomicAdd(&colsums[128 + c2 * 2 + 1], a.w + b.w + c.w + d.w);
    }
}

__global__ void bn_final_k(const float* __restrict__ colsums, const float* __restrict__ gamma,
                           const float* __restrict__ beta, float* __restrict__ bnp) {
    int c = threadIdx.x;   // 128 threads
    float mu = colsums[c] / (float)N_NODES;
    float var = colsums[128 + c] / (float)N_NODES - mu * mu;
    float sc = gamma[c] * rsqrtf(var + 1e-5f);
    bnp[c] = sc;
    bnp[128 + c] = beta[c] - mu * sc;
}

__global__ void bn_apply_k(const uint32_t* __restrict__ G2, const float* __restrict__ bnp,
                           uint32_t* __restrict__ H2) {
    const int total = N_NODES * 64;
    for (int i = blockIdx.x * blockDim.x + threadIdx.x; i < total;
         i += gridDim.x * blockDim.x) {
        int c = (i & 63) * 2;
        uint32_t v = G2[i];
        float f0 = bflo(v) * bnp[c] + bnp[128 + c];
        float f1 = bfhi(v) * bnp[c + 1] + bnp[128 + c + 1];
        f0 = f0 > 0.f ? f0 : 0.f;
        f1 = f1 > 0.f ? f1 : 0.f;
        H2[i] = pack2(f0, f1);
    }
}

// ---------------- launch ---------------------------------------------------
// Workspace (~42.4 MB): cnt@0, cursor@200000, colsums@400000, scantmp@401024,
// rowptr@402048, adj@602052, bufA@3802064, bufB@16602064, bufC@29402064,
// Wc@42202064, bnp@42398672
extern "C" void kernel_launch(void* const* d_in, const int* in_sizes, int n_in,
                              void* d_out, int out_size, void* d_ws, size_t ws_size,
                              hipStream_t stream)
{
    const float* x      = (const float*)d_in[0];
    const int*   ei     = (const int*)d_in[1];
    const float* Wl0    = (const float*)d_in[2];
    const float* bl0    = (const float*)d_in[3];
    const float* Wr0    = (const float*)d_in[4];
    const float* Wl1    = (const float*)d_in[5];
    const float* bl1    = (const float*)d_in[6];
    const float* Wr1    = (const float*)d_in[7];
    const float* Wl2    = (const float*)d_in[8];
    const float* bl2    = (const float*)d_in[9];
    const float* Wr2    = (const float*)d_in[10];
    const float* gamma1 = (const float*)d_in[11];
    const float* beta1  = (const float*)d_in[12];

    char* ws = (char*)d_ws;
    int*      cnt     = (int*)(ws + 0);
    int*      cursor  = (int*)(ws + 200000);
    float*    colsums = (float*)(ws + 400000);
    int*      scantmp = (int*)(ws + 401024);
    int*      rowptr  = (int*)(ws + 402048);
    int*      adj     = (int*)(ws + 602052);
    uint32_t* bufA    = (uint32_t*)(ws + 3802064);
    uint32_t* bufB    = (uint32_t*)(ws + 16602064);
    uint32_t* bufC    = (uint32_t*)(ws + 29402064);
    uint32_t* Wc      = (uint32_t*)(ws + 42202064);
    float*    bnp     = (float*)(ws + 42398672);
    // liveness-based aliases
    uint32_t* X0 = bufA;   // dead after gemm<0>
    uint32_t* MB = bufB;   // mean scratch each layer
    uint32_t* G1 = bufC;   // dead after gemm<1>
    uint32_t* G2 = bufA;
    uint32_t* H2 = bufC;

    const int* srcI = ei;
    const int* dstI = ei + N_EDGES;

    hipMemsetAsync(ws, 0, 401024, stream);   // cnt + cursor + colsums
    prep_k<<<2048, 256, 0, stream>>>(x, Wl0, Wr0, Wl1, Wr1, Wl2, Wr2, X0, Wc);
    degree_k<<<3125, 256, 0, stream>>>(dstI, cnt);
    scan1_k<<<196, 256, 0, stream>>>(cnt, scantmp);
    scan2_k<<<1, 256, 0, stream>>>(scantmp);
    scan3_k<<<196, 256, 0, stream>>>(cnt, scantmp, rowptr);
    fill_adj_k<<<3125, 256, 0, stream>>>(srcI, dstI, rowptr, cursor, adj);

    // Layer 0
    agg_k<<<12500, 256, 0, stream>>>(X0, rowptr, adj, MB);
    gemm_k<0><<<391, 256, 0, stream>>>(MB, X0, Wc, bl0, (void*)G1);
    // Layer 1
    agg_k<<<12500, 256, 0, stream>>>(G1, rowptr, adj, MB);
    gemm_k<1><<<391, 256, 0, stream>>>(MB, G1, Wc, bl1, (void*)G2);
    bn_stats_k<<<512, 256, 0, stream>>>(G2, colsums);
    bn_final_k<<<1, 128, 0, stream>>>(colsums, gamma1, beta1, bnp);
    bn_apply_k<<<2048, 256, 0, stream>>>(G2, bnp, H2);
    // Layer 2
    agg_k<<<12500, 256, 0, stream>>>(H2, rowptr, adj, MB);
    gemm_k<2><<<391, 256, 0, stream>>>(MB, H2, Wc, bl2, d_out);
}

// Round 3
// 385.953 us; speedup vs baseline: 1.2349x; 1.2349x over previous
//
#include <hip/hip_runtime.h>
#include <hip/hip_bf16.h>
#include <cstdint>

#define N_NODES 50000
#define N_EDGES 800000
#define D 128

typedef __attribute__((ext_vector_type(4))) float f32x4;
typedef __attribute__((ext_vector_type(8))) short s16x8;

__device__ __forceinline__ float bflo(uint32_t v) { return __uint_as_float(v << 16); }
__device__ __forceinline__ float bfhi(uint32_t v) { return __uint_as_float(v & 0xffff0000u); }
__device__ __forceinline__ uint32_t f2b(float f) {
    uint32_t x = __float_as_uint(f);
    uint32_t r = x + 0x7fffu + ((x >> 16) & 1u);   // RNE to bf16
    return r >> 16;
}
__device__ __forceinline__ uint32_t pack2(float lo, float hi) {
    return f2b(lo) | (f2b(hi) << 16);
}

// ---------------- prep: x -> bf16, weights -> concatenated bf16 [Wl|Wr] ----
__global__ void prep_k(const float* __restrict__ x,
                       const float* __restrict__ Wl0, const float* __restrict__ Wr0,
                       const float* __restrict__ Wl1, const float* __restrict__ Wr1,
                       const float* __restrict__ Wl2, const float* __restrict__ Wr2,
                       uint32_t* __restrict__ X0, uint32_t* __restrict__ Wc)
{
    const int NX = N_NODES * D / 2;      // 3,200,000 uints
    const int NW = 3 * 128 * 128;        // 49,152 uints
    for (int i = blockIdx.x * blockDim.x + threadIdx.x; i < NX + NW;
         i += gridDim.x * blockDim.x) {
        if (i < NX) {
            const float2 v = reinterpret_cast<const float2*>(x)[i];
            X0[i] = pack2(v.x, v.y);
        } else {
            int j = i - NX;
            int l = j / 16384;
            int r = j % 16384;
            int n = r >> 7;
            int k2 = (r & 127) * 2;
            const float* Wl = (l == 0) ? Wl0 : (l == 1) ? Wl1 : Wl2;
            const float* Wr = (l == 0) ? Wr0 : (l == 1) ? Wr1 : Wr2;
            float a, b;
            if (k2 < 128) { a = Wl[n * 128 + k2];       b = Wl[n * 128 + k2 + 1]; }
            else          { a = Wr[n * 128 + k2 - 128]; b = Wr[n * 128 + k2 - 127]; }
            Wc[j] = pack2(a, b);
        }
    }
}

// ---------------- CSR build ------------------------------------------------
__global__ void degree_k(const int* __restrict__ dst, int* __restrict__ cnt) {
    int e = blockIdx.x * blockDim.x + threadIdx.x;
    if (e < N_EDGES) atomicAdd(&cnt[dst[e]], 1);
}

__global__ void scan1_k(const int* __restrict__ cnt, int* __restrict__ bsum) {
    __shared__ int red[256];
    int i = blockIdx.x * 256 + threadIdx.x;
    int v = (i < N_NODES) ? cnt[i] : 0;
    red[threadIdx.x] = v;
    __syncthreads();
    for (int s = 128; s > 0; s >>= 1) {
        if (threadIdx.x < s) red[threadIdx.x] += red[threadIdx.x + s];
        __syncthreads();
    }
    if (threadIdx.x == 0) bsum[blockIdx.x] = red[0];
}

__global__ void scan2_k(int* __restrict__ bsum) {   // 196 entries -> exclusive
    __shared__ int s[256];
    int t = threadIdx.x;
    int v = (t < 196) ? bsum[t] : 0;
    s[t] = v;
    __syncthreads();
    for (int d = 1; d < 256; d <<= 1) {
        int tmp = (t >= d) ? s[t - d] : 0;
        __syncthreads();
        s[t] += tmp;
        __syncthreads();
    }
    if (t < 196) bsum[t] = s[t] - v;
}

__global__ void scan3_k(const int* __restrict__ cnt, const int* __restrict__ bsum,
                        int* __restrict__ rowptr) {
    __shared__ int s[256];
    int i = blockIdx.x * 256 + threadIdx.x;
    int t = threadIdx.x;
    int v = (i < N_NODES) ? cnt[i] : 0;
    s[t] = v;
    __syncthreads();
    for (int d = 1; d < 256; d <<= 1) {
        int tmp = (t >= d) ? s[t - d] : 0;
        __syncthreads();
        s[t] += tmp;
        __syncthreads();
    }
    if (i < N_NODES) rowptr[i] = bsum[blockIdx.x] + s[t] - v;
    if (i == 0) rowptr[N_NODES] = N_EDGES;
}

__global__ void fill_adj_k(const int* __restrict__ src, const int* __restrict__ dst,
                           const int* __restrict__ rowptr, int* __restrict__ cursor,
                           int* __restrict__ adj) {
    int e = blockIdx.x * blockDim.x + threadIdx.x;
    if (e < N_EDGES) {
        int d = dst[e];
        int pos = atomicAdd(&cursor[d], 1);
        adj[rowptr[d] + pos] = src[e];
    }
}

// ---------------- mean aggregation: one wave per node, 16B lanes -----------
// 16 lanes cover one 256B row; sub = lane>>4 picks one of 4 neighbors per
// group; 2 groups (8 edges) in flight per inner iteration for MLP.
__global__ __launch_bounds__(256) void agg_k(const uint32_t* __restrict__ inB,
                                             const int* __restrict__ rowptr,
                                             const int* __restrict__ adj,
                                             uint32_t* __restrict__ meanb)
{
    const int wid = threadIdx.x >> 6;
    const int lane = threadIdx.x & 63;
    const int n = blockIdx.x * 4 + wid;
    if (n >= N_NODES) return;
    const int start = rowptr[n], end = rowptr[n + 1];
    const int sub = lane >> 4;     // 0..3
    const int col4 = lane & 15;    // 4-uint (16B) chunk within row

    float acc[8];
#pragma unroll
    for (int k = 0; k < 8; ++k) acc[k] = 0.f;

    for (int base = start; base < end; base += 64) {
        int cnt = end - base;
        if (cnt > 64) cnt = 64;
        int idx = (base + lane < end) ? adj[base + lane] : 0;
        for (int j = 0; j < cnt; j += 8) {
            int e0 = j + sub;
            int e1 = j + 4 + sub;
            int s0 = __shfl(idx, e0, 64);
            int s1 = __shfl(idx, e1, 64);
            bool v0 = e0 < cnt;
            bool v1 = e1 < cnt;
            uint4 a = *reinterpret_cast<const uint4*>(inB + (v0 ? s0 : 0) * 64 + col4 * 4);
            uint4 b = *reinterpret_cast<const uint4*>(inB + (v1 ? s1 : 0) * 64 + col4 * 4);
            if (!v0) a = make_uint4(0, 0, 0, 0);
            if (!v1) b = make_uint4(0, 0, 0, 0);
            acc[0] += bflo(a.x); acc[1] += bfhi(a.x);
            acc[2] += bflo(a.y); acc[3] += bfhi(a.y);
            acc[4] += bflo(a.z); acc[5] += bfhi(a.z);
            acc[6] += bflo(a.w); acc[7] += bfhi(a.w);
            acc[0] += bflo(b.x); acc[1] += bfhi(b.x);
            acc[2] += bflo(b.y); acc[3] += bfhi(b.y);
            acc[4] += bflo(b.z); acc[5] += bfhi(b.z);
            acc[6] += bflo(b.w); acc[7] += bfhi(b.w);
        }
    }

    // combine the 4 sub-groups (lanes i, i+16, i+32, i+48 hold same columns)
#pragma unroll
    for (int k = 0; k < 8; ++k) {
        acc[k] += __shfl_xor(acc[k], 16, 64);
        acc[k] += __shfl_xor(acc[k], 32, 64);
    }

    if (sub == 0) {
        int deg = end - start;
        float sc = 1.0f / (float)(deg > 0 ? deg : 1);
        uint4 w;
        w.x = pack2(acc[0] * sc, acc[1] * sc);
        w.y = pack2(acc[2] * sc, acc[3] * sc);
        w.z = pack2(acc[4] * sc, acc[5] * sc);
        w.w = pack2(acc[6] * sc, acc[7] * sc);
        *reinterpret_cast<uint4*>(meanb + n * 64 + col4 * 4) = w;
    }
}

// ---------------- fused GEMM: [mean | in] @ [Wl | Wr]^T + bias -------------
// B (256x128 bf16 = 64KB) staged in LDS with 16B XOR swizzle to kill the
// 512B-row-stride bank conflict on ds_read_b128.
template <int LAYER>
__global__ __launch_bounds__(256) void gemm_k(const uint32_t* __restrict__ meanb,
                                              const uint32_t* __restrict__ inB,
                                              const uint32_t* __restrict__ Wc,
                                              const float* __restrict__ bias,
                                              void* __restrict__ outp)
{
    __shared__ uint32_t Bs[16384];   // 64 KB
    const int t = threadIdx.x;
    const uint32_t* Wg = Wc + LAYER * 16384;
    {
        // thread t stages row r = t>>1, half h = t&1 (64 uints) in 16B chunks
        const int r = t >> 1;
        const int h = t & 1;
        const int sw = (r & 7) << 2;          // XOR swizzle, uint units
#pragma unroll
        for (int q = 0; q < 16; ++q) {
            int off = h * 64 + q * 4;
            *reinterpret_cast<uint4*>(Bs + r * 128 + (off ^ sw)) =
                *reinterpret_cast<const uint4*>(Wg + r * 128 + off);
        }
    }
    __syncthreads();

    const int lane = t & 63;
    const int wid = t >> 6;
    const int rowBase = blockIdx.x * 128 + wid * 32;
    const int l15 = lane & 15;
    const int kc = lane >> 4;
    int m0 = rowBase + l15;
    int m1 = m0 + 16;
    int m0c = m0 < N_NODES ? m0 : N_NODES - 1;
    int m1c = m1 < N_NODES ? m1 : N_NODES - 1;

    f32x4 acc[2][8];
#pragma unroll
    for (int a = 0; a < 2; ++a)
#pragma unroll
        for (int b = 0; b < 8; ++b) acc[a][b] = (f32x4){0.f, 0.f, 0.f, 0.f};

#pragma unroll
    for (int ks = 0; ks < 8; ++ks) {
        const uint32_t* Asrc = (ks < 4) ? meanb : inB;
        const int koff = (ks & 3) * 16 + kc * 4;
        s16x8 a0 = *reinterpret_cast<const s16x8*>(Asrc + m0c * 64 + koff);
        s16x8 a1 = *reinterpret_cast<const s16x8*>(Asrc + m1c * 64 + koff);
#pragma unroll
        for (int nf = 0; nf < 8; ++nf) {
            const int row = nf * 16 + l15;
            const int off = (ks * 16 + kc * 4) ^ ((row & 7) << 2);
            s16x8 b = *reinterpret_cast<const s16x8*>(Bs + row * 128 + off);
            acc[0][nf] = __builtin_amdgcn_mfma_f32_16x16x32_bf16(a0, b, acc[0][nf], 0, 0, 0);
            acc[1][nf] = __builtin_amdgcn_mfma_f32_16x16x32_bf16(a1, b, acc[1][nf], 0, 0, 0);
        }
    }

    const int rb = rowBase + (lane >> 4) * 4;
#pragma unroll
    for (int mf = 0; mf < 2; ++mf) {
#pragma unroll
        for (int nf = 0; nf < 8; ++nf) {
            int col = nf * 16 + l15;
            float bia = bias[col];
#pragma unroll
            for (int r = 0; r < 4; ++r) {
                int row = rb + mf * 16 + r;
                if (row < N_NODES) {
                    float v = acc[mf][nf][r] + bia;
                    if (LAYER == 0) v = v > 0.f ? v : 0.f;
                    if (LAYER == 2)
                        ((float*)outp)[row * 128 + col] = v;
                    else
                        ((unsigned short*)outp)[row * 128 + col] = (unsigned short)f2b(v);
                }
            }
        }
    }
}

// ---------------- BatchNorm ------------------------------------------------
__global__ void bn_stats_k(const uint32_t* __restrict__ G2, float* __restrict__ colsums) {
    __shared__ float4 red[256];
    int c2 = threadIdx.x & 63;
    int rg = threadIdx.x >> 6;
    float s0 = 0, q0 = 0, s1 = 0, q1 = 0;
    for (int r = blockIdx.x * 4 + rg; r < N_NODES; r += gridDim.x * 4) {
        uint32_t v = G2[r * 64 + c2];
        float f0 = bflo(v), f1 = bfhi(v);
        s0 += f0; q0 += f0 * f0;
        s1 += f1; q1 += f1 * f1;
    }
    red[threadIdx.x] = make_float4(s0, q0, s1, q1);
    __syncthreads();
    if (threadIdx.x < 64) {
        float4 a = red[threadIdx.x], b = red[threadIdx.x + 64];
        float4 c = red[threadIdx.x + 128], d = red[threadIdx.x + 192];
        atomicAdd(&colsums[c2 * 2],       a.x + b.x + c.x + d.x);
        atomicAdd(&colsums[c2 * 2 + 1],   a.z + b.z + c.z + d.z);
        atomicAdd(&colsums[128 + c2 * 2],     a.y + b.y + c.y + d.y);
        atomicAdd(&colsums[128 + c2 * 2 + 1], a.w + b.w + c.w + d.w);
    }
}

__global__ void bn_final_k(const float* __restrict__ colsums, const float* __restrict__ gamma,
                           const float* __restrict__ beta, float* __restrict__ bnp) {
    int c = threadIdx.x;   // 128 threads
    float mu = colsums[c] / (float)N_NODES;
    float var = colsums[128 + c] / (float)N_NODES - mu * mu;
    float sc = gamma[c] * rsqrtf(var + 1e-5f);
    bnp[c] = sc;
    bnp[128 + c] = beta[c] - mu * sc;
}

__global__ void bn_apply_k(const uint32_t* __restrict__ G2, const float* __restrict__ bnp,
                           uint32_t* __restrict__ H2) {
    const int total = N_NODES * 64;
    for (int i = blockIdx.x * blockDim.x + threadIdx.x; i < total;
         i += gridDim.x * blockDim.x) {
        int c = (i & 63) * 2;
        uint32_t v = G2[i];
        float f0 = bflo(v) * bnp[c] + bnp[128 + c];
        float f1 = bfhi(v) * bnp[c + 1] + bnp[128 + c + 1];
        f0 = f0 > 0.f ? f0 : 0.f;
        f1 = f1 > 0.f ? f1 : 0.f;
        H2[i] = pack2(f0, f1);
    }
}

// ---------------- launch ---------------------------------------------------
// Workspace (~42.4 MB): cnt@0, cursor@200000, colsums@400000, scantmp@401024,
// rowptr@402048, adj@602052, bufA@3802064, bufB@16602064, bufC@29402064,
// Wc@42202064, bnp@42398672
extern "C" void kernel_launch(void* const* d_in, const int* in_sizes, int n_in,
                              void* d_out, int out_size, void* d_ws, size_t ws_size,
                              hipStream_t stream)
{
    const float* x      = (const float*)d_in[0];
    const int*   ei     = (const int*)d_in[1];
    const float* Wl0    = (const float*)d_in[2];
    const float* bl0    = (const float*)d_in[3];
    const float* Wr0    = (const float*)d_in[4];
    const float* Wl1    = (const float*)d_in[5];
    const float* bl1    = (const float*)d_in[6];
    const float* Wr1    = (const float*)d_in[7];
    const float* Wl2    = (const float*)d_in[8];
    const float* bl2    = (const float*)d_in[9];
    const float* Wr2    = (const float*)d_in[10];
    const float* gamma1 = (const float*)d_in[11];
    const float* beta1  = (const float*)d_in[12];

    char* ws = (char*)d_ws;
    int*      cnt     = (int*)(ws + 0);
    int*      cursor  = (int*)(ws + 200000);
    float*    colsums = (float*)(ws + 400000);
    int*      scantmp = (int*)(ws + 401024);
    int*      rowptr  = (int*)(ws + 402048);
    int*      adj     = (int*)(ws + 602052);
    uint32_t* bufA    = (uint32_t*)(ws + 3802064);
    uint32_t* bufB    = (uint32_t*)(ws + 16602064);
    uint32_t* bufC    = (uint32_t*)(ws + 29402064);
    uint32_t* Wc      = (uint32_t*)(ws + 42202064);
    float*    bnp     = (float*)(ws + 42398672);
    // liveness-based aliases
    uint32_t* X0 = bufA;   // dead after gemm<0>
    uint32_t* MB = bufB;   // mean scratch each layer
    uint32_t* G1 = bufC;   // dead after gemm<1>
    uint32_t* G2 = bufA;
    uint32_t* H2 = bufC;

    const int* srcI = ei;
    const int* dstI = ei + N_EDGES;

    hipMemsetAsync(ws, 0, 401024, stream);   // cnt + cursor + colsums
    prep_k<<<2048, 256, 0, stream>>>(x, Wl0, Wr0, Wl1, Wr1, Wl2, Wr2, X0, Wc);
    degree_k<<<3125, 256, 0, stream>>>(dstI, cnt);
    scan1_k<<<196, 256, 0, stream>>>(cnt, scantmp);
    scan2_k<<<1, 256, 0, stream>>>(scantmp);
    scan3_k<<<196, 256, 0, stream>>>(cnt, scantmp, rowptr);
    fill_adj_k<<<3125, 256, 0, stream>>>(srcI, dstI, rowptr, cursor, adj);

    // Layer 0
    agg_k<<<12500, 256, 0, stream>>>(X0, rowptr, adj, MB);
    gemm_k<0><<<391, 256, 0, stream>>>(MB, X0, Wc, bl0, (void*)G1);
    // Layer 1
    agg_k<<<12500, 256, 0, stream>>>(G1, rowptr, adj, MB);
    gemm_k<1><<<391, 256, 0, stream>>>(MB, G1, Wc, bl1, (void*)G2);
    bn_stats_k<<<512, 256, 0, stream>>>(G2, colsums);
    bn_final_k<<<1, 128, 0, stream>>>(colsums, gamma1, beta1, bnp);
    bn_apply_k<<<2048, 256, 0, stream>>>(G2, bnp, H2);
    // Layer 2
    agg_k<<<12500, 256, 0, stream>>>(H2, rowptr, adj, MB);
    gemm_k<2><<<391, 256, 0, stream>>>(MB, H2, Wc, bl2, d_out);
}

// Round 9
// 306.241 us; speedup vs baseline: 1.5563x; 1.2603x over previous
//
#include <hip/hip_runtime.h>
#include <hip/hip_bf16.h>
#include <cstdint>

#define N_NODES 50000
#define N_EDGES 800000
#define D 128
#define NBUCK 196          // ceil(50000 / 256), bucket = dst >> 8
#define CAP 4608           // per-bucket capacity; mean 4096, sigma 64 -> 8 sigma slack

typedef __attribute__((ext_vector_type(4))) float f32x4;
typedef __attribute__((ext_vector_type(8))) short s16x8;

__device__ __forceinline__ float bflo(uint32_t v) { return __uint_as_float(v << 16); }
__device__ __forceinline__ float bfhi(uint32_t v) { return __uint_as_float(v & 0xffff0000u); }
__device__ __forceinline__ uint32_t f2b(float f) {
    uint32_t x = __float_as_uint(f);
    uint32_t r = x + 0x7fffu + ((x >> 16) & 1u);   // RNE to bf16
    return r >> 16;
}
__device__ __forceinline__ uint32_t pack2(float lo, float hi) {
    return f2b(lo) | (f2b(hi) << 16);
}

// ---------------- prep: x -> bf16, weights -> concatenated bf16 [Wl|Wr] ----
__global__ void prep_k(const float* __restrict__ x,
                       const float* __restrict__ Wl0, const float* __restrict__ Wr0,
                       const float* __restrict__ Wl1, const float* __restrict__ Wr1,
                       const float* __restrict__ Wl2, const float* __restrict__ Wr2,
                       uint32_t* __restrict__ X0, uint32_t* __restrict__ Wc)
{
    const int NX = N_NODES * D / 2;      // 3,200,000 uints
    const int NW = 3 * 128 * 128;        // 49,152 uints
    for (int i = blockIdx.x * blockDim.x + threadIdx.x; i < NX + NW;
         i += gridDim.x * blockDim.x) {
        if (i < NX) {
            const float2 v = reinterpret_cast<const float2*>(x)[i];
            X0[i] = pack2(v.x, v.y);
        } else {
            int j = i - NX;
            int l = j / 16384;
            int r = j % 16384;
            int n = r >> 7;
            int k2 = (r & 127) * 2;
            const float* Wl = (l == 0) ? Wl0 : (l == 1) ? Wl1 : Wl2;
            const float* Wr = (l == 0) ? Wr0 : (l == 1) ? Wr1 : Wr2;
            float a, b;
            if (k2 < 128) { a = Wl[n * 128 + k2];       b = Wl[n * 128 + k2 + 1]; }
            else          { a = Wr[n * 128 + k2 - 128]; b = Wr[n * 128 + k2 - 127]; }
            Wc[j] = pack2(a, b);
        }
    }
}

// ---------------- CSR build via 2-level bucket sort ------------------------
// Pass 1: bucket by dst>>8. Per-block LDS histogram -> one global atomic per
// bucket per block -> scatter (src,dst) to contiguous per-block segments.
__global__ __launch_bounds__(256) void bucket_k(const int* __restrict__ src,
                                                const int* __restrict__ dst,
                                                int* __restrict__ bcnt,
                                                uint2* __restrict__ ebuf)
{
    __shared__ int h[256], base[256], cur[256];
    const int t = threadIdx.x;
    h[t] = 0; cur[t] = 0;
    __syncthreads();
    const int chunk = (N_EDGES + gridDim.x - 1) / gridDim.x;
    const int e0 = blockIdx.x * chunk;
    int e1 = e0 + chunk; if (e1 > N_EDGES) e1 = N_EDGES;
    for (int e = e0 + t; e < e1; e += 256) {
        int b = dst[e] >> 8;
        atomicAdd(&h[b], 1);
    }
    __syncthreads();
    if (t < NBUCK) base[t] = (h[t] > 0) ? atomicAdd(&bcnt[t], h[t]) : 0;
    __syncthreads();
    for (int e = e0 + t; e < e1; e += 256) {
        int s = src[e], d = dst[e];
        int b = d >> 8;
        int r = atomicAdd(&cur[b], 1);
        int pos = base[b] + r;
        if (pos < CAP) ebuf[b * CAP + pos] = make_uint2((uint32_t)s, (uint32_t)d);
    }
}

// Pass 2: exclusive scan of the 196 bucket counts.
__global__ void bscan_k(const int* __restrict__ bcnt, int* __restrict__ bbase) {
    __shared__ int s[256];
    int t = threadIdx.x;
    int v = (t < NBUCK) ? bcnt[t] : 0;
    s[t] = v;
    __syncthreads();
    for (int d = 1; d < 256; d <<= 1) {
        int tmp = (t >= d) ? s[t - d] : 0;
        __syncthreads();
        s[t] += tmp;
        __syncthreads();
    }
    if (t < NBUCK) bbase[t] = s[t] - v;
}

// Pass 3: one block per bucket. All edges of the bucket's 256 nodes are
// local; build fine CSR in LDS, write rowptr coalesced + adj within a
// 16KB window.
__global__ __launch_bounds__(256) void csr_k(const uint2* __restrict__ ebuf,
                                             const int* __restrict__ bcnt,
                                             const int* __restrict__ bbase,
                                             int* __restrict__ rowptr,
                                             int* __restrict__ adj)
{
    __shared__ int cntL[256], offL[256], curL[256];
    const int b = blockIdx.x;
    const int t = threadIdx.x;
    const int n0 = b << 8;
    const int m = bcnt[b];
    const int gbase = bbase[b];
    cntL[t] = 0; curL[t] = 0;
    __syncthreads();
    const uint2* eb = ebuf + b * CAP;
    for (int i = t; i < m; i += 256)
        atomicAdd(&cntL[(int)eb[i].y - n0], 1);
    __syncthreads();
    int v = cntL[t];
    offL[t] = v;
    __syncthreads();
    for (int d = 1; d < 256; d <<= 1) {
        int tmp = (t >= d) ? offL[t - d] : 0;
        __syncthreads();
        offL[t] += tmp;
        __syncthreads();
    }
    int excl = offL[t] - v;       // exclusive scan value
    int node = n0 + t;
    if (node < N_NODES) rowptr[node] = gbase + excl;
    if (b == NBUCK - 1 && t == 0) rowptr[N_NODES] = N_EDGES;
    __syncthreads();
    offL[t] = excl;
    __syncthreads();
    for (int i = t; i < m; i += 256) {
        uint2 e = eb[i];
        int d = (int)e.y - n0;
        int r = atomicAdd(&curL[d], 1);
        adj[gbase + offL[d] + r] = (int)e.x;
    }
}

// ---------------- mean aggregation: one wave per node, 16B lanes -----------
__global__ __launch_bounds__(256) void agg_k(const uint32_t* __restrict__ inB,
                                             const int* __restrict__ rowptr,
                                             const int* __restrict__ adj,
                                             uint32_t* __restrict__ meanb)
{
    const int wid = threadIdx.x >> 6;
    const int lane = threadIdx.x & 63;
    const int n = blockIdx.x * 4 + wid;
    if (n >= N_NODES) return;
    const int start = rowptr[n], end = rowptr[n + 1];
    const int sub = lane >> 4;     // 0..3
    const int col4 = lane & 15;    // 4-uint (16B) chunk within row

    float acc[8];
#pragma unroll
    for (int k = 0; k < 8; ++k) acc[k] = 0.f;

    for (int base = start; base < end; base += 64) {
        int cnt = end - base;
        if (cnt > 64) cnt = 64;
        int idx = (base + lane < end) ? adj[base + lane] : 0;
        for (int j = 0; j < cnt; j += 8) {
            int e0 = j + sub;
            int e1 = j + 4 + sub;
            int s0 = __shfl(idx, e0, 64);
            int s1 = __shfl(idx, e1, 64);
            bool v0 = e0 < cnt;
            bool v1 = e1 < cnt;
            uint4 a = *reinterpret_cast<const uint4*>(inB + (v0 ? s0 : 0) * 64 + col4 * 4);
            uint4 b = *reinterpret_cast<const uint4*>(inB + (v1 ? s1 : 0) * 64 + col4 * 4);
            if (!v0) a = make_uint4(0, 0, 0, 0);
            if (!v1) b = make_uint4(0, 0, 0, 0);
            acc[0] += bflo(a.x); acc[1] += bfhi(a.x);
            acc[2] += bflo(a.y); acc[3] += bfhi(a.y);
            acc[4] += bflo(a.z); acc[5] += bfhi(a.z);
            acc[6] += bflo(a.w); acc[7] += bfhi(a.w);
            acc[0] += bflo(b.x); acc[1] += bfhi(b.x);
            acc[2] += bflo(b.y); acc[3] += bfhi(b.y);
            acc[4] += bflo(b.z); acc[5] += bfhi(b.z);
            acc[6] += bflo(b.w); acc[7] += bfhi(b.w);
        }
    }

#pragma unroll
    for (int k = 0; k < 8; ++k) {
        acc[k] += __shfl_xor(acc[k], 16, 64);
        acc[k] += __shfl_xor(acc[k], 32, 64);
    }

    if (sub == 0) {
        int deg = end - start;
        float sc = 1.0f / (float)(deg > 0 ? deg : 1);
        uint4 w;
        w.x = pack2(acc[0] * sc, acc[1] * sc);
        w.y = pack2(acc[2] * sc, acc[3] * sc);
        w.z = pack2(acc[4] * sc, acc[5] * sc);
        w.w = pack2(acc[6] * sc, acc[7] * sc);
        *reinterpret_cast<uint4*>(meanb + n * 64 + col4 * 4) = w;
    }
}

// ---------------- fused GEMM: [mean | in] @ [Wl | Wr]^T + bias -------------
template <int LAYER>
__global__ __launch_bounds__(256) void gemm_k(const uint32_t* __restrict__ meanb,
                                              const uint32_t* __restrict__ inB,
                                              const uint32_t* __restrict__ Wc,
                                              const float* __restrict__ bias,
                                              void* __restrict__ outp)
{
    __shared__ uint32_t Bs[16384];   // 64 KB
    const int t = threadIdx.x;
    const uint32_t* Wg = Wc + LAYER * 16384;
    {
        const int r = t >> 1;
        const int h = t & 1;
        const int sw = (r & 7) << 2;          // XOR swizzle, uint units
#pragma unroll
        for (int q = 0; q < 16; ++q) {
            int off = h * 64 + q * 4;
            *reinterpret_cast<uint4*>(Bs + r * 128 + (off ^ sw)) =
                *reinterpret_cast<const uint4*>(Wg + r * 128 + off);
        }
    }
    __syncthreads();

    const int lane = t & 63;
    const int wid = t >> 6;
    const int rowBase = blockIdx.x * 128 + wid * 32;
    const int l15 = lane & 15;
    const int kc = lane >> 4;
    int m0 = rowBase + l15;
    int m1 = m0 + 16;
    int m0c = m0 < N_NODES ? m0 : N_NODES - 1;
    int m1c = m1 < N_NODES ? m1 : N_NODES - 1;

    f32x4 acc[2][8];
#pragma unroll
    for (int a = 0; a < 2; ++a)
#pragma unroll
        for (int b = 0; b < 8; ++b) acc[a][b] = (f32x4){0.f, 0.f, 0.f, 0.f};

#pragma unroll
    for (int ks = 0; ks < 8; ++ks) {
        const uint32_t* Asrc = (ks < 4) ? meanb : inB;
        const int koff = (ks & 3) * 16 + kc * 4;
        s16x8 a0 = *reinterpret_cast<const s16x8*>(Asrc + m0c * 64 + koff);
        s16x8 a1 = *reinterpret_cast<const s16x8*>(Asrc + m1c * 64 + koff);
#pragma unroll
        for (int nf = 0; nf < 8; ++nf) {
            const int row = nf * 16 + l15;
            const int off = (ks * 16 + kc * 4) ^ ((row & 7) << 2);
            s16x8 b = *reinterpret_cast<const s16x8*>(Bs + row * 128 + off);
            acc[0][nf] = __builtin_amdgcn_mfma_f32_16x16x32_bf16(a0, b, acc[0][nf], 0, 0, 0);
            acc[1][nf] = __builtin_amdgcn_mfma_f32_16x16x32_bf16(a1, b, acc[1][nf], 0, 0, 0);
        }
    }

    const int rb = rowBase + (lane >> 4) * 4;
#pragma unroll
    for (int mf = 0; mf < 2; ++mf) {
#pragma unroll
        for (int nf = 0; nf < 8; ++nf) {
            int col = nf * 16 + l15;
            float bia = bias[col];
#pragma unroll
            for (int r = 0; r < 4; ++r) {
                int row = rb + mf * 16 + r;
                if (row < N_NODES) {
                    float v = acc[mf][nf][r] + bia;
                    if (LAYER == 0) v = v > 0.f ? v : 0.f;
                    if (LAYER == 2)
                        ((float*)outp)[row * 128 + col] = v;
                    else
                        ((unsigned short*)outp)[row * 128 + col] = (unsigned short)f2b(v);
                }
            }
        }
    }
}

// ---------------- BatchNorm ------------------------------------------------
__global__ void bn_stats_k(const uint32_t* __restrict__ G2, float* __restrict__ colsums) {
    __shared__ float4 red[256];
    int c2 = threadIdx.x & 63;
    int rg = threadIdx.x >> 6;
    float s0 = 0, q0 = 0, s1 = 0, q1 = 0;
    for (int r = blockIdx.x * 4 + rg; r < N_NODES; r += gridDim.x * 4) {
        uint32_t v = G2[r * 64 + c2];
        float f0 = bflo(v), f1 = bfhi(v);
        s0 += f0; q0 += f0 * f0;
        s1 += f1; q1 += f1 * f1;
    }
    red[threadIdx.x] = make_float4(s0, q0, s1, q1);
    __syncthreads();
    if (threadIdx.x < 64) {
        float4 a = red[threadIdx.x], b = red[threadIdx.x + 64];
        float4 c = red[threadIdx.x + 128], d = red[threadIdx.x + 192];
        atomicAdd(&colsums[c2 * 2],       a.x + b.x + c.x + d.x);
        atomicAdd(&colsums[c2 * 2 + 1],   a.z + b.z + c.z + d.z);
        atomicAdd(&colsums[128 + c2 * 2],     a.y + b.y + c.y + d.y);
        atomicAdd(&colsums[128 + c2 * 2 + 1], a.w + b.w + c.w + d.w);
    }
}

__global__ void bn_final_k(const float* __restrict__ colsums, const float* __restrict__ gamma,
                           const float* __restrict__ beta, float* __restrict__ bnp) {
    int c = threadIdx.x;   // 128 threads
    float mu = colsums[c] / (float)N_NODES;
    float var = colsums[128 + c] / (float)N_NODES - mu * mu;
    float sc = gamma[c] * rsqrtf(var + 1e-5f);
    bnp[c] = sc;
    bnp[128 + c] = beta[c] - mu * sc;
}

__global__ void bn_apply_k(const uint32_t* __restrict__ G2, const float* __restrict__ bnp,
                           uint32_t* __restrict__ H2) {
    const int total = N_NODES * 64;
    for (int i = blockIdx.x * blockDim.x + threadIdx.x; i < total;
         i += gridDim.x * blockDim.x) {
        int c = (i & 63) * 2;
        uint32_t v = G2[i];
        float f0 = bflo(v) * bnp[c] + bnp[128 + c];
        float f1 = bfhi(v) * bnp[c + 1] + bnp[128 + c + 1];
        f0 = f0 > 0.f ? f0 : 0.f;
        f1 = f1 > 0.f ? f1 : 0.f;
        H2[i] = pack2(f0, f1);
    }
}

// ---------------- launch ---------------------------------------------------
// Workspace (~49.2 MB):
//   bcnt    @ 0          (784, pad 1024)   [zeroed]
//   colsums @ 1024       (1024)            [zeroed]
//   bbase   @ 2048       (1024)
//   rowptr  @ 4096       (200,004)
//   adj     @ 204,160    (3,200,000)
//   ebuf    @ 3,404,160  (7,225,344 = 196*4608*8)
//   bufA    @ 10,629,504 (12.8 MB)
//   bufB    @ 23,429,504 (12.8 MB)
//   bufC    @ 36,229,504 (12.8 MB)
//   Wc      @ 49,029,504 (196,608)
//   bnp     @ 49,226,112 (1,024)
extern "C" void kernel_launch(void* const* d_in, const int* in_sizes, int n_in,
                              void* d_out, int out_size, void* d_ws, size_t ws_size,
                              hipStream_t stream)
{
    const float* x      = (const float*)d_in[0];
    const int*   ei     = (const int*)d_in[1];
    const float* Wl0    = (const float*)d_in[2];
    const float* bl0    = (const float*)d_in[3];
    const float* Wr0    = (const float*)d_in[4];
    const float* Wl1    = (const float*)d_in[5];
    const float* bl1    = (const float*)d_in[6];
    const float* Wr1    = (const float*)d_in[7];
    const float* Wl2    = (const float*)d_in[8];
    const float* bl2    = (const float*)d_in[9];
    const float* Wr2    = (const float*)d_in[10];
    const float* gamma1 = (const float*)d_in[11];
    const float* beta1  = (const float*)d_in[12];

    char* ws = (char*)d_ws;
    int*      bcnt    = (int*)(ws + 0);
    float*    colsums = (float*)(ws + 1024);
    int*      bbase   = (int*)(ws + 2048);
    int*      rowptr  = (int*)(ws + 4096);
    int*      adj     = (int*)(ws + 204160);
    uint2*    ebuf    = (uint2*)(ws + 3404160);
    uint32_t* bufA    = (uint32_t*)(ws + 10629504);
    uint32_t* bufB    = (uint32_t*)(ws + 23429504);
    uint32_t* bufC    = (uint32_t*)(ws + 36229504);
    uint32_t* Wc      = (uint32_t*)(ws + 49029504);
    float*    bnp     = (float*)(ws + 49226112);
    // liveness-based aliases
    uint32_t* X0 = bufA;   // dead after gemm<0>
    uint32_t* MB = bufB;   // mean scratch each layer
    uint32_t* G1 = bufC;   // dead after gemm<1>
    uint32_t* G2 = bufA;
    uint32_t* H2 = bufC;

    const int* srcI = ei;
    const int* dstI = ei + N_EDGES;

    hipMemsetAsync(ws, 0, 2048, stream);   // bcnt + colsums
    prep_k<<<2048, 256, 0, stream>>>(x, Wl0, Wr0, Wl1, Wr1, Wl2, Wr2, X0, Wc);
    bucket_k<<<512, 256, 0, stream>>>(srcI, dstI, bcnt, ebuf);
    bscan_k<<<1, 256, 0, stream>>>(bcnt, bbase);
    csr_k<<<NBUCK, 256, 0, stream>>>(ebuf, bcnt, bbase, rowptr, adj);

    // Layer 0
    agg_k<<<12500, 256, 0, stream>>>(X0, rowptr, adj, MB);
    gemm_k<0><<<391, 256, 0, stream>>>(MB, X0, Wc, bl0, (void*)G1);
    // Layer 1
    agg_k<<<12500, 256, 0, stream>>>(G1, rowptr, adj, MB);
    gemm_k<1><<<391, 256, 0, stream>>>(MB, G1, Wc, bl1, (void*)G2);
    bn_stats_k<<<512, 256, 0, stream>>>(G2, colsums);
    bn_final_k<<<1, 128, 0, stream>>>(colsums, gamma1, beta1, bnp);
    bn_apply_k<<<2048, 256, 0, stream>>>(G2, bnp, H2);
    // Layer 2
    agg_k<<<12500, 256, 0, stream>>>(H2, rowptr, adj, MB);
    gemm_k<2><<<391, 256, 0, stream>>>(MB, H2, Wc, bl2, d_out);
}

// Round 10
// 281.591 us; speedup vs baseline: 1.6926x; 1.0875x over previous
//
#include <hip/hip_runtime.h>
#include <hip/hip_bf16.h>
#include <cstdint>

#define N_NODES 50000
#define N_EDGES 800000
#define D 128
#define NBUCK 196          // ceil(50000 / 256), bucket = dst >> 8
#define CAP 4608           // per-bucket capacity; mean 4096, sigma 64 -> 8 sigma slack

typedef __attribute__((ext_vector_type(4))) float f32x4;
typedef __attribute__((ext_vector_type(8))) short s16x8;

__device__ __forceinline__ float bflo(uint32_t v) { return __uint_as_float(v << 16); }
__device__ __forceinline__ float bfhi(uint32_t v) { return __uint_as_float(v & 0xffff0000u); }
__device__ __forceinline__ uint32_t f2b(float f) {
    uint32_t x = __float_as_uint(f);
    uint32_t r = x + 0x7fffu + ((x >> 16) & 1u);   // RNE to bf16
    return r >> 16;
}
__device__ __forceinline__ uint32_t pack2(float lo, float hi) {
    return f2b(lo) | (f2b(hi) << 16);
}

// ---------------- packed: prep (x->bf16, weights->bf16) + edge bucketing ---
// blocks [0,512): bucket by dst>>8 (LDS histogram -> 1 atomic/bucket/block ->
//                 contiguous per-block segments of each bucket)
// blocks [512,2560): grid-stride convert x and weights
__global__ __launch_bounds__(256) void pb_k(const float* __restrict__ x,
                       const float* __restrict__ Wl0, const float* __restrict__ Wr0,
                       const float* __restrict__ Wl1, const float* __restrict__ Wr1,
                       const float* __restrict__ Wl2, const float* __restrict__ Wr2,
                       uint32_t* __restrict__ X0, uint32_t* __restrict__ Wc,
                       const int* __restrict__ src, const int* __restrict__ dst,
                       int* __restrict__ bcnt, uint2* __restrict__ ebuf)
{
    const int t = threadIdx.x;
    if (blockIdx.x < 512) {
        __shared__ int h[256], base[256], cur[256];
        h[t] = 0; cur[t] = 0;
        __syncthreads();
        const int chunk = (N_EDGES + 511) / 512;
        const int e0 = blockIdx.x * chunk;
        int e1 = e0 + chunk; if (e1 > N_EDGES) e1 = N_EDGES;
        for (int e = e0 + t; e < e1; e += 256) {
            int b = dst[e] >> 8;
            atomicAdd(&h[b], 1);
        }
        __syncthreads();
        if (t < NBUCK) base[t] = (h[t] > 0) ? atomicAdd(&bcnt[t], h[t]) : 0;
        __syncthreads();
        for (int e = e0 + t; e < e1; e += 256) {
            int s = src[e], d = dst[e];
            int b = d >> 8;
            int r = atomicAdd(&cur[b], 1);
            int pos = base[b] + r;
            if (pos < CAP) ebuf[b * CAP + pos] = make_uint2((uint32_t)s, (uint32_t)d);
        }
    } else {
        const int NX = N_NODES * D / 2;      // 3,200,000 uints
        const int NW = 3 * 128 * 128;        // 49,152 uints
        const int bid = blockIdx.x - 512;    // 0..2047
        for (int i = bid * 256 + t; i < NX + NW; i += 2048 * 256) {
            if (i < NX) {
                const float2 v = reinterpret_cast<const float2*>(x)[i];
                X0[i] = pack2(v.x, v.y);
            } else {
                int j = i - NX;
                int l = j / 16384;
                int r = j % 16384;
                int n = r >> 7;
                int k2 = (r & 127) * 2;
                const float* Wl = (l == 0) ? Wl0 : (l == 1) ? Wl1 : Wl2;
                const float* Wr = (l == 0) ? Wr0 : (l == 1) ? Wr1 : Wr2;
                float a, b;
                if (k2 < 128) { a = Wl[n * 128 + k2];       b = Wl[n * 128 + k2 + 1]; }
                else          { a = Wr[n * 128 + k2 - 128]; b = Wr[n * 128 + k2 - 127]; }
                Wc[j] = pack2(a, b);
            }
        }
    }
}

// ---------------- CSR: one block per bucket, self-scans bucket counts ------
__global__ __launch_bounds__(256) void csr_k(const uint2* __restrict__ ebuf,
                                             const int* __restrict__ bcnt,
                                             int* __restrict__ rowptr,
                                             int* __restrict__ adj)
{
    __shared__ int bs[256], cntL[256], offL[256], curL[256];
    const int b = blockIdx.x;
    const int t = threadIdx.x;
    const int n0 = b << 8;
    // self-scan of the 196 bucket counts (inclusive -> exclusive base)
    int bv = (t < NBUCK) ? bcnt[t] : 0;
    bs[t] = bv;
    __syncthreads();
    for (int d = 1; d < 256; d <<= 1) {
        int tmp = (t >= d) ? bs[t - d] : 0;
        __syncthreads();
        bs[t] += tmp;
        __syncthreads();
    }
    const int gbase = (b == 0) ? 0 : bs[b - 1];
    const int m = bcnt[b];
    cntL[t] = 0; curL[t] = 0;
    __syncthreads();
    const uint2* eb = ebuf + b * CAP;
    for (int i = t; i < m; i += 256)
        atomicAdd(&cntL[(int)eb[i].y - n0], 1);
    __syncthreads();
    int v = cntL[t];
    offL[t] = v;
    __syncthreads();
    for (int d = 1; d < 256; d <<= 1) {
        int tmp = (t >= d) ? offL[t - d] : 0;
        __syncthreads();
        offL[t] += tmp;
        __syncthreads();
    }
    int excl = offL[t] - v;       // exclusive scan value
    int node = n0 + t;
    if (node < N_NODES) rowptr[node] = gbase + excl;
    if (b == NBUCK - 1 && t == 0) rowptr[N_NODES] = N_EDGES;
    __syncthreads();
    offL[t] = excl;
    __syncthreads();
    for (int i = t; i < m; i += 256) {
        uint2 e = eb[i];
        int d = (int)e.y - n0;
        int r = atomicAdd(&curL[d], 1);
        adj[gbase + offL[d] + r] = (int)e.x;
    }
}

// ---------------- mean aggregation: one wave per node, 16B lanes -----------
// APPLYBN=1: gathered elements get relu(g*sc+sh) before accumulation (BN
// derived per block from colsums/gamma/beta); masking applied AFTER the
// affine so zero-padded slots contribute 0.
template <int APPLYBN>
__global__ __launch_bounds__(256) void agg_k(const uint32_t* __restrict__ inB,
                                             const int* __restrict__ rowptr,
                                             const int* __restrict__ adj,
                                             uint32_t* __restrict__ meanb,
                                             const float* __restrict__ colsums,
                                             const float* __restrict__ gamma,
                                             const float* __restrict__ beta)
{
    const int wid = threadIdx.x >> 6;
    const int lane = threadIdx.x & 63;
    const int n = blockIdx.x * 4 + wid;        // grid is exactly 12500*4 = N_NODES
    const int sub = lane >> 4;     // 0..3
    const int col4 = lane & 15;    // 4-uint (16B) chunk within row

    float vsc[8], vsh[8];
    if constexpr (APPLYBN) {
        __shared__ float bnS[256];
        const int t = threadIdx.x;
        if (t < 128) {
            float mu  = colsums[t] * (1.0f / N_NODES);
            float var = colsums[128 + t] * (1.0f / N_NODES) - mu * mu;
            float sc  = gamma[t] * rsqrtf(var + 1e-5f);
            bnS[t] = sc;
            bnS[128 + t] = beta[t] - mu * sc;
        }
        __syncthreads();
#pragma unroll
        for (int k = 0; k < 8; ++k) {
            int c = col4 * 8 + k;
            vsc[k] = bnS[c]; vsh[k] = bnS[128 + c];
        }
    }
    if (n >= N_NODES) return;

    const int start = rowptr[n], end = rowptr[n + 1];
    float acc[8];
#pragma unroll
    for (int k = 0; k < 8; ++k) acc[k] = 0.f;

    for (int base = start; base < end; base += 64) {
        int cnt = end - base;
        if (cnt > 64) cnt = 64;
        int idx = (base + lane < end) ? adj[base + lane] : 0;
        for (int j = 0; j < cnt; j += 8) {
            int e0 = j + sub;
            int e1 = j + 4 + sub;
            int s0 = __shfl(idx, e0, 64);
            int s1 = __shfl(idx, e1, 64);
            bool v0 = e0 < cnt;
            bool v1 = e1 < cnt;
            uint4 a = *reinterpret_cast<const uint4*>(inB + (v0 ? s0 : 0) * 64 + col4 * 4);
            uint4 b = *reinterpret_cast<const uint4*>(inB + (v1 ? s1 : 0) * 64 + col4 * 4);
            if constexpr (APPLYBN) {
                float m0 = v0 ? 1.f : 0.f;
                float m1 = v1 ? 1.f : 0.f;
#define ACCBN(K, GA, GB) acc[K] += m0 * fmaxf(fmaf((GA), vsc[K], vsh[K]), 0.f) \
                                 + m1 * fmaxf(fmaf((GB), vsc[K], vsh[K]), 0.f)
                ACCBN(0, bflo(a.x), bflo(b.x)); ACCBN(1, bfhi(a.x), bfhi(b.x));
                ACCBN(2, bflo(a.y), bflo(b.y)); ACCBN(3, bfhi(a.y), bfhi(b.y));
                ACCBN(4, bflo(a.z), bflo(b.z)); ACCBN(5, bfhi(a.z), bfhi(b.z));
                ACCBN(6, bflo(a.w), bflo(b.w)); ACCBN(7, bfhi(a.w), bfhi(b.w));
#undef ACCBN
            } else {
                if (!v0) a = make_uint4(0, 0, 0, 0);
                if (!v1) b = make_uint4(0, 0, 0, 0);
                acc[0] += bflo(a.x); acc[1] += bfhi(a.x);
                acc[2] += bflo(a.y); acc[3] += bfhi(a.y);
                acc[4] += bflo(a.z); acc[5] += bfhi(a.z);
                acc[6] += bflo(a.w); acc[7] += bfhi(a.w);
                acc[0] += bflo(b.x); acc[1] += bfhi(b.x);
                acc[2] += bflo(b.y); acc[3] += bfhi(b.y);
                acc[4] += bflo(b.z); acc[5] += bfhi(b.z);
                acc[6] += bflo(b.w); acc[7] += bfhi(b.w);
            }
        }
    }

#pragma unroll
    for (int k = 0; k < 8; ++k) {
        acc[k] += __shfl_xor(acc[k], 16, 64);
        acc[k] += __shfl_xor(acc[k], 32, 64);
    }

    if (sub == 0) {
        int deg = end - start;
        float sc = 1.0f / (float)(deg > 0 ? deg : 1);
        uint4 w;
        w.x = pack2(acc[0] * sc, acc[1] * sc);
        w.y = pack2(acc[2] * sc, acc[3] * sc);
        w.z = pack2(acc[4] * sc, acc[5] * sc);
        w.w = pack2(acc[6] * sc, acc[7] * sc);
        *reinterpret_cast<uint4*>(meanb + n * 64 + col4 * 4) = w;
    }
}

// ---------------- fused GEMM: [mean | in] @ [Wl | Wr]^T + bias -------------
// LAYER 0: +relu, bf16 out.  LAYER 1: bf16 out + BN col-stats into colsums
// (LDS reduce -> 256 global atomics/block).  LAYER 2: self-path (inB = G2)
// gets relu(BN(.)) applied in-register before MFMA; fp32 out.
__device__ __forceinline__ s16x8 bn8(uint4 u, const float* bnS, int cb) {
    uint32_t uu[4] = {u.x, u.y, u.z, u.w};
    uint32_t w[4];
#pragma unroll
    for (int i = 0; i < 4; ++i) {
        int c = cb + 2 * i;
        float lo = fmaxf(fmaf(bflo(uu[i]), bnS[c],     bnS[128 + c]),     0.f);
        float hi = fmaxf(fmaf(bfhi(uu[i]), bnS[c + 1], bnS[128 + c + 1]), 0.f);
        w[i] = pack2(lo, hi);
    }
    uint4 r = make_uint4(w[0], w[1], w[2], w[3]);
    return __builtin_bit_cast(s16x8, r);
}

template <int LAYER>
__global__ __launch_bounds__(256) void gemm_k(const uint32_t* __restrict__ meanb,
                                              const uint32_t* __restrict__ inB,
                                              const uint32_t* __restrict__ Wc,
                                              const float* __restrict__ bias,
                                              void* __restrict__ outp,
                                              float* __restrict__ colsums,
                                              const float* __restrict__ gamma,
                                              const float* __restrict__ beta)
{
    __shared__ uint32_t Bs[16384];   // 64 KB weights
    __shared__ float extraS[256];    // L1: col {sum,sumsq}; L2: {sc,sh}
    const int t = threadIdx.x;
    const uint32_t* Wg = Wc + LAYER * 16384;
    {
        const int r = t >> 1;
        const int h = t & 1;
        const int sw = (r & 7) << 2;          // XOR swizzle, uint units
#pragma unroll
        for (int q = 0; q < 16; ++q) {
            int off = h * 64 + q * 4;
            *reinterpret_cast<uint4*>(Bs + r * 128 + (off ^ sw)) =
                *reinterpret_cast<const uint4*>(Wg + r * 128 + off);
        }
    }
    if constexpr (LAYER == 1) {
        extraS[t] = 0.f;
    }
    if constexpr (LAYER == 2) {
        if (t < 128) {
            float mu  = colsums[t] * (1.0f / N_NODES);
            float var = colsums[128 + t] * (1.0f / N_NODES) - mu * mu;
            float sc  = gamma[t] * rsqrtf(var + 1e-5f);
            extraS[t] = sc;
            extraS[128 + t] = beta[t] - mu * sc;
        }
    }
    __syncthreads();

    const int lane = t & 63;
    const int wid = t >> 6;
    const int rowBase = blockIdx.x * 128 + wid * 32;
    const int l15 = lane & 15;
    const int kc = lane >> 4;
    int m0 = rowBase + l15;
    int m1 = m0 + 16;
    int m0c = m0 < N_NODES ? m0 : N_NODES - 1;
    int m1c = m1 < N_NODES ? m1 : N_NODES - 1;

    f32x4 acc[2][8];
#pragma unroll
    for (int a = 0; a < 2; ++a)
#pragma unroll
        for (int b = 0; b < 8; ++b) acc[a][b] = (f32x4){0.f, 0.f, 0.f, 0.f};

#pragma unroll
    for (int ks = 0; ks < 8; ++ks) {
        const int koff = (ks & 3) * 16 + kc * 4;
        s16x8 a0, a1;
        if (ks < 4) {
            a0 = *reinterpret_cast<const s16x8*>(meanb + m0c * 64 + koff);
            a1 = *reinterpret_cast<const s16x8*>(meanb + m1c * 64 + koff);
        } else {
            if constexpr (LAYER == 2) {
                const int cb = (ks & 3) * 32 + kc * 8;
                uint4 u0 = *reinterpret_cast<const uint4*>(inB + m0c * 64 + koff);
                uint4 u1 = *reinterpret_cast<const uint4*>(inB + m1c * 64 + koff);
                a0 = bn8(u0, extraS, cb);
                a1 = bn8(u1, extraS, cb);
            } else {
                a0 = *reinterpret_cast<const s16x8*>(inB + m0c * 64 + koff);
                a1 = *reinterpret_cast<const s16x8*>(inB + m1c * 64 + koff);
            }
        }
#pragma unroll
        for (int nf = 0; nf < 8; ++nf) {
            const int row = nf * 16 + l15;
            const int off = (ks * 16 + kc * 4) ^ ((row & 7) << 2);
            s16x8 b = *reinterpret_cast<const s16x8*>(Bs + row * 128 + off);
            acc[0][nf] = __builtin_amdgcn_mfma_f32_16x16x32_bf16(a0, b, acc[0][nf], 0, 0, 0);
            acc[1][nf] = __builtin_amdgcn_mfma_f32_16x16x32_bf16(a1, b, acc[1][nf], 0, 0, 0);
        }
    }

    const int rb = rowBase + (lane >> 4) * 4;
#pragma unroll
    for (int nf = 0; nf < 8; ++nf) {
        int col = nf * 16 + l15;
        float bia = bias[col];
        float s = 0.f, q = 0.f;
#pragma unroll
        for (int mf = 0; mf < 2; ++mf) {
#pragma unroll
            for (int r = 0; r < 4; ++r) {
                int row = rb + mf * 16 + r;
                if (row < N_NODES) {
                    float v = acc[mf][nf][r] + bia;
                    if (LAYER == 0) v = v > 0.f ? v : 0.f;
                    if (LAYER == 2)
                        ((float*)outp)[row * 128 + col] = v;
                    else
                        ((unsigned short*)outp)[row * 128 + col] = (unsigned short)f2b(v);
                    if constexpr (LAYER == 1) { s += v; q += v * v; }
                }
            }
        }
        if constexpr (LAYER == 1) {
            atomicAdd(&extraS[col], s);
            atomicAdd(&extraS[128 + col], q);
        }
    }
    if constexpr (LAYER == 1) {
        __syncthreads();
        if (t < 128) {
            atomicAdd(&colsums[t], extraS[t]);
            atomicAdd(&colsums[128 + t], extraS[128 + t]);
        }
    }
}

// ---------------- launch ---------------------------------------------------
// Workspace (~49.2 MB):
//   bcnt    @ 0          (784, pad 1024)   [zeroed]
//   colsums @ 1024       (1024)            [zeroed]
//   rowptr  @ 4096       (200,004)
//   adj     @ 204,160    (3,200,000)
//   ebuf    @ 3,404,160  (7,225,344 = 196*4608*8)
//   bufA    @ 10,629,504 (12.8 MB)  X0, later G2
//   bufB    @ 23,429,504 (12.8 MB)  MB (mean scratch)
//   bufC    @ 36,229,504 (12.8 MB)  G1
//   Wc      @ 49,029,504 (196,608)
extern "C" void kernel_launch(void* const* d_in, const int* in_sizes, int n_in,
                              void* d_out, int out_size, void* d_ws, size_t ws_size,
                              hipStream_t stream)
{
    const float* x      = (const float*)d_in[0];
    const int*   ei     = (const int*)d_in[1];
    const float* Wl0    = (const float*)d_in[2];
    const float* bl0    = (const float*)d_in[3];
    const float* Wr0    = (const float*)d_in[4];
    const float* Wl1    = (const float*)d_in[5];
    const float* bl1    = (const float*)d_in[6];
    const float* Wr1    = (const float*)d_in[7];
    const float* Wl2    = (const float*)d_in[8];
    const float* bl2    = (const float*)d_in[9];
    const float* Wr2    = (const float*)d_in[10];
    const float* gamma1 = (const float*)d_in[11];
    const float* beta1  = (const float*)d_in[12];

    char* ws = (char*)d_ws;
    int*      bcnt    = (int*)(ws + 0);
    float*    colsums = (float*)(ws + 1024);
    int*      rowptr  = (int*)(ws + 4096);
    int*      adj     = (int*)(ws + 204160);
    uint2*    ebuf    = (uint2*)(ws + 3404160);
    uint32_t* bufA    = (uint32_t*)(ws + 10629504);
    uint32_t* bufB    = (uint32_t*)(ws + 23429504);
    uint32_t* bufC    = (uint32_t*)(ws + 36229504);
    uint32_t* Wc      = (uint32_t*)(ws + 49029504);
    // liveness-based aliases
    uint32_t* X0 = bufA;   // dead after gemm<0>
    uint32_t* MB = bufB;   // mean scratch each layer
    uint32_t* G1 = bufC;   // dead after gemm<1>
    uint32_t* G2 = bufA;

    const int* srcI = ei;
    const int* dstI = ei + N_EDGES;

    hipMemsetAsync(ws, 0, 2048, stream);   // bcnt + colsums
    pb_k<<<2560, 256, 0, stream>>>(x, Wl0, Wr0, Wl1, Wr1, Wl2, Wr2, X0, Wc,
                                   srcI, dstI, bcnt, ebuf);
    csr_k<<<NBUCK, 256, 0, stream>>>(ebuf, bcnt, rowptr, adj);

    // Layer 0
    agg_k<0><<<12500, 256, 0, stream>>>(X0, rowptr, adj, MB, nullptr, nullptr, nullptr);
    gemm_k<0><<<391, 256, 0, stream>>>(MB, X0, Wc, bl0, (void*)G1, nullptr, nullptr, nullptr);
    // Layer 1 (+BN stats in epilogue)
    agg_k<0><<<12500, 256, 0, stream>>>(G1, rowptr, adj, MB, nullptr, nullptr, nullptr);
    gemm_k<1><<<391, 256, 0, stream>>>(MB, G1, Wc, bl1, (void*)G2, colsums, nullptr, nullptr);
    // Layer 2 (BN+relu applied inline: gathers in agg, self-path in gemm)
    agg_k<1><<<12500, 256, 0, stream>>>(G2, rowptr, adj, MB, colsums, gamma1, beta1);
    gemm_k<2><<<391, 256, 0, stream>>>(MB, G2, Wc, bl2, d_out, colsums, gamma1, beta1);
}